// Round 1
// baseline (182.256 us; speedup 1.0000x reference)
//
#include <hip/hip_runtime.h>

#define N_NODES 50000
#define N_EDGES 800000
#define D 128
#define NB 391                 // buckets: bucket = dst >> 7, 128 nodes each
#define CAPB 4928              // fixed slots per bucket (mean 2046, ~64 sigma)
#define P1B 256                // partition blocks in k_a
#define EPB ((N_EDGES + P1B - 1) / P1B)  // 3125 edges/block
#define CAP 28                 // LDS staging slots per bucket in partition role
#define WPB 16                 // weight-pack blocks
#define XC0 (P1B + WPB + 1)    // first xcast block = 273
#define KA_BLOCKS (XC0 + (N_NODES * 16) / 256)  // 273 + 3125 = 3398

typedef __attribute__((ext_vector_type(8))) short short8;
typedef __attribute__((ext_vector_type(4))) float f32x4;

// round-to-nearest-even f32 -> bf16 (as ushort)
__device__ __forceinline__ unsigned short f2bf(float f) {
    unsigned int u = __builtin_bit_cast(unsigned int, f);
    u += 0x7FFFu + ((u >> 16) & 1u);
    return (unsigned short)(u >> 16);
}
__device__ __forceinline__ float bf2f(unsigned short h) {
    unsigned int u = ((unsigned int)h) << 16;
    return __builtin_bit_cast(float, u);
}

// ---------------------------------------------------------------------------
// gcur[b] = 0 (relative per-bucket fill counters; bases are fixed b*CAPB)
__global__ void k_init(int* __restrict__ gcur) {
    const int t = threadIdx.x;
    if (t < NB) gcur[t] = 0;
}

// ---------------------------------------------------------------------------
// Fused independent front-end:
//   blocks [0,256): edge partition into fixed-base buckets (LDS write-combine)
//   blocks [256,272): pack Wab = [Wc + Wc@Wt ; W0 - Wt] into bf16 B-fragments
//   block 272: bv = bc + bc@Wt
//   blocks [273,...): xb[n] = bf16(x[n])   (no dinv dependency!)
__global__ __launch_bounds__(256) void k_a(const int* __restrict__ src,
                                           const int* __restrict__ dst,
                                           int* __restrict__ gcur,
                                           unsigned int* __restrict__ pbuf,
                                           const float* __restrict__ Wc,
                                           const float* __restrict__ W0,
                                           const float* __restrict__ Wt,
                                           const float* __restrict__ bc,
                                           const float* __restrict__ x,
                                           unsigned short* __restrict__ Wp,
                                           float* __restrict__ bv,
                                           unsigned short* __restrict__ xb) {
    __shared__ float sWt[D * D];  // 64 KB; aliased as staging by partition role
    const int t = threadIdx.x;
    const unsigned int bid = blockIdx.x;

    if (bid < P1B) {  // ---- edge partition role ----
        unsigned int (*stage)[CAP + 1] =
            reinterpret_cast<unsigned int(*)[CAP + 1]>(sWt);      // 391*29*4 B
        int* scnt = reinterpret_cast<int*>(sWt) + NB * (CAP + 1); // +391*4 B
        for (int i = t; i < NB; i += 256) scnt[i] = 0;
        __syncthreads();

        const long e0 = (long)bid * EPB;
        const long e1 = (e0 + EPB < N_EDGES) ? e0 + EPB : N_EDGES;
        for (long e = e0 + t; e < e1; e += 256) {
            const int s = src[e];
            const int d = dst[e];
            const int b = d >> 7;
            const unsigned int p = ((unsigned int)(d & 127) << 16) | (unsigned int)s;
            const int slot = atomicAdd(&scnt[b], 1);
            if (slot < CAP) {
                stage[b][slot] = p;
            } else {  // spill (statistically ~never; correct for any distribution)
                pbuf[(long)b * CAPB + atomicAdd(&gcur[b], 1)] = p;
            }
        }
        __syncthreads();
        for (int bb = t; bb < NB; bb += 256) {
            const int n = (scnt[bb] < CAP) ? scnt[bb] : CAP;
            if (n > 0) {
                const int pos = bb * CAPB + atomicAdd(&gcur[bb], n);
                for (int i = 0; i < n; ++i) pbuf[pos + i] = stage[bb][i];
            }
        }
        return;
    }

    if (bid < P1B + WPB) {  // ---- weight pack role ----
        for (int i = t * 4; i < D * D; i += 256 * 4)
            *(float4*)(sWt + i) = *(const float4*)(Wt + i);
        __syncthreads();
        const int id = (int)(bid - P1B) * 256 + t;  // 0..4095
        const int lane = id & 63;
        const int tile = (id >> 6) & 7;
        const int step = id >> 9;
        const int n = tile * 16 + (lane & 15);
        const int kbase = step * 32 + (lane >> 4) * 8;
        unsigned short v[8];
#pragma unroll
        for (int j = 0; j < 8; ++j) {
            const int k = kbase + j;
            float f;
            if (k < D) {
                f = Wc[k * D + n];
#pragma unroll 16
                for (int m = 0; m < D; ++m) f += Wc[k * D + m] * sWt[m * D + n];
            } else {
                f = W0[(k - D) * D + n] - sWt[(k - D) * D + n];
            }
            v[j] = f2bf(f);
        }
        *(uint4*)(Wp + (long)id * 8) = *(uint4*)v;
        return;
    }

    if (bid == P1B + WPB) {  // ---- bias role ----
        if (t < D) {
            float acc = bc[t];
#pragma unroll 16
            for (int k = 0; k < D; ++k) acc += bc[k] * Wt[k * D + t];
            bv[t] = acc;
        }
        return;
    }

    // ---- xcast role: xb = bf16(x) ----
    const int gid = (int)(bid - XC0) * 256 + t;  // 0 .. N*16-1
    const int node = gid >> 4;
    const int c = gid & 15;
    const float4 a = ((const float4*)x)[(long)node * 32 + c * 2];
    const float4 b = ((const float4*)x)[(long)node * 32 + c * 2 + 1];
    const float f[8] = {a.x, a.y, a.z, a.w, b.x, b.y, b.z, b.w};
    unsigned short vb[8];
#pragma unroll
    for (int j = 0; j < 8; ++j) vb[j] = f2bf(f[j]);
    *(uint4*)(xb + (long)node * 128 + c * 8) = *(uint4*)vb;
}

// ---------------------------------------------------------------------------
// Per-bucket local CSR build (128-node buckets): hist + scan in LDS, scatter
// into L2-local window. Produces row_start / cnt / dinv.
__global__ __launch_bounds__(256) void k_part2(const unsigned int* __restrict__ pbuf,
                                               const int* __restrict__ gcur,
                                               int* __restrict__ row_start,
                                               int* __restrict__ cnt,
                                               float* __restrict__ dinv,
                                               int* __restrict__ esrc) {
    __shared__ int lcnt[128];
    __shared__ int lcur[128];
    __shared__ int stmp[128];
    const int b = blockIdx.x;
    const int t = threadIdx.x;
    const int base = b * CAPB;
    const int n = gcur[b];  // relative count

    if (t < 128) lcnt[t] = 0;
    __syncthreads();
    for (int i = t; i < n; i += 256) atomicAdd(&lcnt[pbuf[base + i] >> 16], 1);
    __syncthreads();

    int c = 0;
    if (t < 128) {
        c = lcnt[t];
        stmp[t] = c;
    }
    __syncthreads();
    for (int off = 1; off < 128; off <<= 1) {
        int u = (t >= off && t < 128) ? stmp[t - off] : 0;
        __syncthreads();
        if (t < 128) stmp[t] += u;
        __syncthreads();
    }
    if (t < 128) {
        const int ls = base + stmp[t] - c;  // exclusive, within bucket window
        lcur[t] = ls;
        const int node = b * 128 + t;
        if (node < N_NODES) {
            row_start[node] = ls;
            cnt[node] = c;
            dinv[node] = rsqrtf((float)c + 1.0f);
        }
    }
    __syncthreads();

    for (int i = t; i < n; i += 256) {
        const unsigned int p = pbuf[base + i];
        const int pos = atomicAdd(&lcur[p >> 16], 1);
        esrc[pos] = (int)(p & 0xFFFFu);
    }
}

// ---------------------------------------------------------------------------
// Fused gather + GEMM. Block = 64 rows.
// Phase 1: wave w gathers nodes w*16..w*16+15 (4 edge slots x 16 chunks, dinv
//          applied per edge), writes bf16 g-rows into XOR-swizzled LDS tile.
// Phase 2: 4 waves do [64x256] @ Wab[256x128] via 16x16x32 MFMA:
//          k 0..127 from LDS (g), k 128..255 from xb (raw bf16 x).
__global__ __launch_bounds__(256) void k_gmm(const unsigned short* __restrict__ xb,
                                             const int* __restrict__ row_start,
                                             const int* __restrict__ cnt,
                                             const float* __restrict__ dinv,
                                             const int* __restrict__ esrc,
                                             const unsigned short* __restrict__ Wp,
                                             const float* __restrict__ bv,
                                             float* __restrict__ out) {
    __shared__ unsigned short sg[64 * 128];  // 16 KB, rows XOR-swizzled
    const int tid = threadIdx.x;
    const int wave = tid >> 6;
    const int lane = tid & 63;
    const int c = lane & 15;  // 8-elem chunk
    const int s = lane >> 4;  // edge slot
    const int row0 = blockIdx.x * 64;

    for (int m = 0; m < 16; ++m) {
        const int node = row0 + wave * 16 + m;
        const bool valid = node < N_NODES;
        float acc[8] = {};
        if (valid) {
            const int begin = row_start[node];
            const int end = begin + cnt[node];
            int i = begin + s;
            for (; i + 12 < end; i += 16) {  // four edges in flight per slot
                const int a0 = esrc[i];
                const int a1 = esrc[i + 4];
                const int a2 = esrc[i + 8];
                const int a3 = esrc[i + 12];
                const short8 v0 = *(const short8*)(xb + (long)a0 * 128 + c * 8);
                const short8 v1 = *(const short8*)(xb + (long)a1 * 128 + c * 8);
                const short8 v2 = *(const short8*)(xb + (long)a2 * 128 + c * 8);
                const short8 v3 = *(const short8*)(xb + (long)a3 * 128 + c * 8);
                const float d0 = dinv[a0];
                const float d1 = dinv[a1];
                const float d2 = dinv[a2];
                const float d3 = dinv[a3];
#pragma unroll
                for (int j = 0; j < 8; ++j)
                    acc[j] += (d0 * bf2f((unsigned short)v0[j]) +
                               d1 * bf2f((unsigned short)v1[j])) +
                              (d2 * bf2f((unsigned short)v2[j]) +
                               d3 * bf2f((unsigned short)v3[j]));
            }
            for (; i < end; i += 4) {
                const int a0 = esrc[i];
                const float d0 = dinv[a0];
                const short8 v0 = *(const short8*)(xb + (long)a0 * 128 + c * 8);
#pragma unroll
                for (int j = 0; j < 8; ++j) acc[j] += d0 * bf2f((unsigned short)v0[j]);
            }
        }
#pragma unroll
        for (int j = 0; j < 8; ++j) {
            acc[j] += __shfl_xor(acc[j], 16);
            acc[j] += __shfl_xor(acc[j], 32);
        }
        if (s == 0) {
            const int r = wave * 16 + m;  // LDS row
            unsigned short o[8] = {0, 0, 0, 0, 0, 0, 0, 0};
            if (valid) {
                const float di = dinv[node];
                const short8 xs = *(const short8*)(xb + (long)node * 128 + c * 8);
#pragma unroll
                for (int j = 0; j < 8; ++j)
                    o[j] = f2bf(di * (acc[j] + di * bf2f((unsigned short)xs[j])));
            }
            const int col = (c * 16) ^ ((r & 7) << 4);  // swizzled byte offset
            *(uint4*)((char*)sg + r * 256 + col) = *(uint4*)o;
        }
    }
    __syncthreads();

    // ---- GEMM phase: wave computes rows row0 + wave*16 .. +15 ----
    const int lr = lane & 15;
    const int quad = lane >> 4;
    const int rloc = wave * 16 + lr;  // LDS row this lane reads
    int ar = row0 + rloc;
    if (ar >= N_NODES) ar = N_NODES - 1;  // clamp loads; stores are guarded
    const unsigned short* aptr = xb + (long)ar * 128 + quad * 8;

    f32x4 acc2[8] = {};
#pragma unroll
    for (int s8 = 0; s8 < 8; ++s8) {
        short8 a;
        if (s8 < 4) {
            const int colb = (s8 * 64 + quad * 16) ^ ((rloc & 7) << 4);
            a = *(const short8*)((const char*)sg + rloc * 256 + colb);
        } else {
            a = *(const short8*)(aptr + (s8 - 4) * 32);
        }
#pragma unroll
        for (int t2 = 0; t2 < 8; ++t2) {
            const short8 b =
                *(const short8*)(Wp + ((long)(s8 * 8 + t2) * 64 + lane) * 8);
            acc2[t2] = __builtin_amdgcn_mfma_f32_16x16x32_bf16(a, b, acc2[t2], 0, 0, 0);
        }
    }

    const int rowbase = row0 + wave * 16;
#pragma unroll
    for (int t2 = 0; t2 < 8; ++t2) {
        const int col = t2 * 16 + lr;
        const float bvv = bv[col];
#pragma unroll
        for (int r = 0; r < 4; ++r) {
            const int row = rowbase + quad * 4 + r;
            if (row < N_NODES) out[(long)row * D + col] = acc2[t2][r] + bvv;
        }
    }
}

// ---------------------------------------------------------------------------
extern "C" void kernel_launch(void* const* d_in, const int* in_sizes, int n_in,
                              void* d_out, int out_size, void* d_ws, size_t ws_size,
                              hipStream_t stream) {
    const float* x  = (const float*)d_in[0];
    const int*   ei = (const int*)d_in[1];  // [2, E] flat: row0=src, row1=dst
    const float* Wc = (const float*)d_in[2];
    const float* bc = (const float*)d_in[3];
    const float* W0 = (const float*)d_in[4];
    const float* Wt = (const float*)d_in[5];
    float* out = (float*)d_out;

    const int* src = ei;
    const int* dst = ei + N_EDGES;

    // workspace layout:
    //   xb bf16 [N*128] | cnt [N] | row_start [N] | dinv [N] |
    //   esrc [NB*CAPB] | pbuf [NB*CAPB] | bv f32 [D] | Wp bf16 [256*128] | gcur [NB]
    unsigned short* xb = (unsigned short*)d_ws;
    int*   cnt        = (int*)(xb + (size_t)N_NODES * 128);
    int*   row_start  = cnt + N_NODES;
    float* dinv       = (float*)(row_start + N_NODES);
    int*   esrc       = (int*)(dinv + N_NODES);
    unsigned int* pbuf = (unsigned int*)(esrc + (size_t)NB * CAPB);
    float* bv         = (float*)(pbuf + (size_t)NB * CAPB);
    unsigned short* Wp = (unsigned short*)(bv + D);
    int*   gcur       = (int*)(Wp + 256 * D);

    k_init<<<1, 512, 0, stream>>>(gcur);
    k_a<<<KA_BLOCKS, 256, 0, stream>>>(src, dst, gcur, pbuf, Wc, W0, Wt, bc, x,
                                       Wp, bv, xb);
    k_part2<<<NB, 256, 0, stream>>>(pbuf, gcur, row_start, cnt, dinv, esrc);
    k_gmm<<<(N_NODES + 63) / 64, 256, 0, stream>>>(xb, row_start, cnt, dinv, esrc,
                                                   Wp, bv, out);
}

// Round 2
// 176.204 us; speedup vs baseline: 1.0343x; 1.0343x over previous
//
#include <hip/hip_runtime.h>

#define N_NODES 50000
#define N_EDGES 800000
#define D 128
#define NB 391                 // buckets: bucket = dst >> 7, 128 nodes each
#define CAPB 4928              // fixed slots per bucket (mean 2046, ~64 sigma)
#define P1B 256                // partition blocks in k_a
#define EPB ((N_EDGES + P1B - 1) / P1B)  // 3125 edges/block
#define CAP 16                 // LDS staging slots per bucket in partition role
#define WPB 16                 // weight-pack blocks
#define XC0 (P1B + WPB + 1)    // first xcast block = 273
#define KA_BLOCKS (XC0 + (N_NODES * 16) / 256)  // 273 + 3125 = 3398

typedef __attribute__((ext_vector_type(8))) short short8;
typedef __attribute__((ext_vector_type(4))) float f32x4;

// round-to-nearest-even f32 -> bf16 (as ushort)
__device__ __forceinline__ unsigned short f2bf(float f) {
    unsigned int u = __builtin_bit_cast(unsigned int, f);
    u += 0x7FFFu + ((u >> 16) & 1u);
    return (unsigned short)(u >> 16);
}
__device__ __forceinline__ float bf2f(unsigned short h) {
    unsigned int u = ((unsigned int)h) << 16;
    return __builtin_bit_cast(float, u);
}

// ---------------------------------------------------------------------------
// gcur[b] = 0 (relative per-bucket fill counters; bases are fixed b*CAPB)
__global__ void k_init(int* __restrict__ gcur) {
    const int t = threadIdx.x;
    if (t < NB) gcur[t] = 0;
}

// ---------------------------------------------------------------------------
// Fused independent front-end (28 KB static LDS -> 5 blocks/CU):
//   blocks [0,256): edge partition into fixed-base buckets (LDS write-combine)
//   blocks [256,272): pack Wab = [Wc + Wc@Wt ; W0 - Wt] into bf16 B-fragments
//                     (Wt read from global/L2 -- no LDS so xcast keeps occupancy)
//   block 272: bv = bc + bc@Wt
//   blocks [273,...): xb[n] = bf16(x[n])   (no dinv dependency)
__global__ __launch_bounds__(256) void k_a(const int* __restrict__ src,
                                           const int* __restrict__ dst,
                                           int* __restrict__ gcur,
                                           unsigned int* __restrict__ pbuf,
                                           const float* __restrict__ Wc,
                                           const float* __restrict__ W0,
                                           const float* __restrict__ Wt,
                                           const float* __restrict__ bc,
                                           const float* __restrict__ x,
                                           unsigned short* __restrict__ Wp,
                                           float* __restrict__ bv,
                                           unsigned short* __restrict__ xb) {
    __shared__ unsigned int stage[NB][CAP + 1];  // 26.6 KB (+1: conflict-free drain)
    __shared__ int scnt[NB];                     // 1.6 KB
    const int t = threadIdx.x;
    const unsigned int bid = blockIdx.x;

    if (bid < P1B) {  // ---- edge partition role ----
        for (int i = t; i < NB; i += 256) scnt[i] = 0;
        __syncthreads();

        const long e0 = (long)bid * EPB;
        const long e1 = (e0 + EPB < N_EDGES) ? e0 + EPB : N_EDGES;
        for (long e = e0 + t; e < e1; e += 256) {
            const int s = src[e];
            const int d = dst[e];
            const int b = d >> 7;
            const unsigned int p = ((unsigned int)(d & 127) << 16) | (unsigned int)s;
            const int slot = atomicAdd(&scnt[b], 1);
            if (slot < CAP) {
                stage[b][slot] = p;
            } else {  // spill (~1-2K edges total at CAP=16; correct for any dist)
                pbuf[(long)b * CAPB + atomicAdd(&gcur[b], 1)] = p;
            }
        }
        __syncthreads();
        for (int bb = t; bb < NB; bb += 256) {
            const int n = (scnt[bb] < CAP) ? scnt[bb] : CAP;
            if (n > 0) {
                const int pos = bb * CAPB + atomicAdd(&gcur[bb], n);
                for (int i = 0; i < n; ++i) pbuf[pos + i] = stage[bb][i];
            }
        }
        return;
    }

    if (bid < P1B + WPB) {  // ---- weight pack role (global Wt, off critical path) ----
        const int id = (int)(bid - P1B) * 256 + t;  // 0..4095
        const int lane = id & 63;
        const int tile = (id >> 6) & 7;
        const int step = id >> 9;
        const int n = tile * 16 + (lane & 15);
        const int kbase = step * 32 + (lane >> 4) * 8;
        float f[8];
#pragma unroll
        for (int j = 0; j < 8; ++j) {
            const int k = kbase + j;
            f[j] = (k < D) ? Wc[k * D + n]
                           : (W0[(k - D) * D + n] - Wt[(k - D) * D + n]);
        }
        if (kbase < D) {  // uniform per block (512 ids per step)
#pragma unroll 8
            for (int m = 0; m < D; ++m) {
                const float wt = Wt[m * D + n];
#pragma unroll
                for (int j = 0; j < 8; ++j) f[j] += Wc[(kbase + j) * D + m] * wt;
            }
        }
        unsigned short v[8];
#pragma unroll
        for (int j = 0; j < 8; ++j) v[j] = f2bf(f[j]);
        *(uint4*)(Wp + (long)id * 8) = *(uint4*)v;
        return;
    }

    if (bid == P1B + WPB) {  // ---- bias role ----
        if (t < D) {
            float acc = bc[t];
#pragma unroll 16
            for (int k = 0; k < D; ++k) acc += bc[k] * Wt[k * D + t];
            bv[t] = acc;
        }
        return;
    }

    // ---- xcast role: xb = bf16(x) ----
    const int gid = (int)(bid - XC0) * 256 + t;  // 0 .. N*16-1
    const int node = gid >> 4;
    const int c = gid & 15;
    const float4 a = ((const float4*)x)[(long)node * 32 + c * 2];
    const float4 b = ((const float4*)x)[(long)node * 32 + c * 2 + 1];
    const float f[8] = {a.x, a.y, a.z, a.w, b.x, b.y, b.z, b.w};
    unsigned short vb[8];
#pragma unroll
    for (int j = 0; j < 8; ++j) vb[j] = f2bf(f[j]);
    *(uint4*)(xb + (long)node * 128 + c * 8) = *(uint4*)vb;
}

// ---------------------------------------------------------------------------
// Per-bucket local CSR build (128-node buckets): hist + scan in LDS, scatter
// into L2-local window. Produces row_start / cnt / dinv.
__global__ __launch_bounds__(256) void k_part2(const unsigned int* __restrict__ pbuf,
                                               const int* __restrict__ gcur,
                                               int* __restrict__ row_start,
                                               int* __restrict__ cnt,
                                               float* __restrict__ dinv,
                                               int* __restrict__ esrc) {
    __shared__ int lcnt[128];
    __shared__ int lcur[128];
    __shared__ int stmp[128];
    const int b = blockIdx.x;
    const int t = threadIdx.x;
    const int base = b * CAPB;
    const int n = gcur[b];  // relative count

    if (t < 128) lcnt[t] = 0;
    __syncthreads();
    for (int i = t; i < n; i += 256) atomicAdd(&lcnt[pbuf[base + i] >> 16], 1);
    __syncthreads();

    int c = 0;
    if (t < 128) {
        c = lcnt[t];
        stmp[t] = c;
    }
    __syncthreads();
    for (int off = 1; off < 128; off <<= 1) {
        int u = (t >= off && t < 128) ? stmp[t - off] : 0;
        __syncthreads();
        if (t < 128) stmp[t] += u;
        __syncthreads();
    }
    if (t < 128) {
        const int ls = base + stmp[t] - c;  // exclusive, within bucket window
        lcur[t] = ls;
        const int node = b * 128 + t;
        if (node < N_NODES) {
            row_start[node] = ls;
            cnt[node] = c;
            dinv[node] = rsqrtf((float)c + 1.0f);
        }
    }
    __syncthreads();

    for (int i = t; i < n; i += 256) {
        const unsigned int p = pbuf[base + i];
        const int pos = atomicAdd(&lcur[p >> 16], 1);
        esrc[pos] = (int)(p & 0xFFFFu);
    }
}

// ---------------------------------------------------------------------------
// Fused gather + GEMM. Block = 64 rows, 512 threads = 8 waves.
// Phase 1: wave w gathers nodes w*8..w*8+7 (4 edge slots x 16 chunks, dinv
//          applied per edge), writes bf16 g-rows into XOR-swizzled LDS tile.
//          8 waves/block + 3 blocks/CU -> ~24 waves/CU to hide gather latency.
// Phase 2: wave w=(wr,wc) computes rows wr*16..+15, cols wc*64..+63 of
//          [64x256] @ Wab[256x128]: k 0..127 from LDS (g), k 128..255 from xb.
__global__ __launch_bounds__(512) void k_gmm(const unsigned short* __restrict__ xb,
                                             const int* __restrict__ row_start,
                                             const int* __restrict__ cnt,
                                             const float* __restrict__ dinv,
                                             const int* __restrict__ esrc,
                                             const unsigned short* __restrict__ Wp,
                                             const float* __restrict__ bv,
                                             float* __restrict__ out) {
    __shared__ unsigned short sg[64 * 128];  // 16 KB, rows XOR-swizzled
    const int tid = threadIdx.x;
    const int wave = tid >> 6;  // 0..7
    const int lane = tid & 63;
    const int c = lane & 15;  // 8-elem chunk
    const int s = lane >> 4;  // edge slot
    const int row0 = blockIdx.x * 64;

    // hoist row ranges for this wave's 8 nodes (fully unrolled -> registers)
    int beg[8], en[8];
#pragma unroll
    for (int m = 0; m < 8; ++m) {
        const int node = row0 + wave * 8 + m;
        const bool v = node < N_NODES;
        const int b0 = v ? row_start[node] : 0;
        beg[m] = b0;
        en[m] = b0 + (v ? cnt[node] : 0);
    }

#pragma unroll
    for (int m = 0; m < 8; ++m) {
        const int node = row0 + wave * 8 + m;
        const bool valid = node < N_NODES;
        float acc[8] = {};
        int i = beg[m] + s;
        const int end = en[m];
        for (; i + 12 < end; i += 16) {  // four edges in flight per slot
            const int a0 = esrc[i];
            const int a1 = esrc[i + 4];
            const int a2 = esrc[i + 8];
            const int a3 = esrc[i + 12];
            const short8 v0 = *(const short8*)(xb + (long)a0 * 128 + c * 8);
            const short8 v1 = *(const short8*)(xb + (long)a1 * 128 + c * 8);
            const short8 v2 = *(const short8*)(xb + (long)a2 * 128 + c * 8);
            const short8 v3 = *(const short8*)(xb + (long)a3 * 128 + c * 8);
            const float d0 = dinv[a0];
            const float d1 = dinv[a1];
            const float d2 = dinv[a2];
            const float d3 = dinv[a3];
#pragma unroll
            for (int j = 0; j < 8; ++j)
                acc[j] += (d0 * bf2f((unsigned short)v0[j]) +
                           d1 * bf2f((unsigned short)v1[j])) +
                          (d2 * bf2f((unsigned short)v2[j]) +
                           d3 * bf2f((unsigned short)v3[j]));
        }
        for (; i < end; i += 4) {
            const int a0 = esrc[i];
            const float d0 = dinv[a0];
            const short8 v0 = *(const short8*)(xb + (long)a0 * 128 + c * 8);
#pragma unroll
            for (int j = 0; j < 8; ++j) acc[j] += d0 * bf2f((unsigned short)v0[j]);
        }
#pragma unroll
        for (int j = 0; j < 8; ++j) {
            acc[j] += __shfl_xor(acc[j], 16);
            acc[j] += __shfl_xor(acc[j], 32);
        }
        if (s == 0) {
            const int r = wave * 8 + m;  // LDS row
            unsigned short o[8] = {0, 0, 0, 0, 0, 0, 0, 0};
            if (valid) {
                const float di = dinv[node];
                const short8 xs = *(const short8*)(xb + (long)node * 128 + c * 8);
#pragma unroll
                for (int j = 0; j < 8; ++j)
                    o[j] = f2bf(di * (acc[j] + di * bf2f((unsigned short)xs[j])));
            }
            const int col = (c * 16) ^ ((r & 7) << 4);  // swizzled byte offset
            *(uint4*)((char*)sg + r * 256 + col) = *(uint4*)o;
        }
    }
    __syncthreads();

    // ---- GEMM phase: wave (wr,wc) -> rows wr*16..+15, cols wc*64..+63 ----
    const int lr = lane & 15;
    const int quad = lane >> 4;
    const int wr = wave & 3;
    const int wc = wave >> 2;
    const int rloc = wr * 16 + lr;  // LDS row this lane reads
    int ar = row0 + rloc;
    if (ar >= N_NODES) ar = N_NODES - 1;  // clamp loads; stores are guarded
    const unsigned short* aptr = xb + (long)ar * 128 + quad * 8;

    f32x4 acc2[4] = {};
#pragma unroll
    for (int s8 = 0; s8 < 8; ++s8) {
        short8 a;
        if (s8 < 4) {
            const int colb = (s8 * 64 + quad * 16) ^ ((rloc & 7) << 4);
            a = *(const short8*)((const char*)sg + rloc * 256 + colb);
        } else {
            a = *(const short8*)(aptr + (s8 - 4) * 32);
        }
#pragma unroll
        for (int t2 = 0; t2 < 4; ++t2) {
            const short8 b =
                *(const short8*)(Wp + ((long)(s8 * 8 + wc * 4 + t2) * 64 + lane) * 8);
            acc2[t2] = __builtin_amdgcn_mfma_f32_16x16x32_bf16(a, b, acc2[t2], 0, 0, 0);
        }
    }

    const int rowbase = row0 + wr * 16;
#pragma unroll
    for (int t2 = 0; t2 < 4; ++t2) {
        const int col = wc * 64 + t2 * 16 + lr;
        const float bvv = bv[col];
#pragma unroll
        for (int r = 0; r < 4; ++r) {
            const int row = rowbase + quad * 4 + r;
            if (row < N_NODES) out[(long)row * D + col] = acc2[t2][r] + bvv;
        }
    }
}

// ---------------------------------------------------------------------------
extern "C" void kernel_launch(void* const* d_in, const int* in_sizes, int n_in,
                              void* d_out, int out_size, void* d_ws, size_t ws_size,
                              hipStream_t stream) {
    const float* x  = (const float*)d_in[0];
    const int*   ei = (const int*)d_in[1];  // [2, E] flat: row0=src, row1=dst
    const float* Wc = (const float*)d_in[2];
    const float* bc = (const float*)d_in[3];
    const float* W0 = (const float*)d_in[4];
    const float* Wt = (const float*)d_in[5];
    float* out = (float*)d_out;

    const int* src = ei;
    const int* dst = ei + N_EDGES;

    // workspace layout:
    //   xb bf16 [N*128] | cnt [N] | row_start [N] | dinv [N] |
    //   esrc [NB*CAPB] | pbuf [NB*CAPB] | bv f32 [D] | Wp bf16 [256*128] | gcur [NB]
    unsigned short* xb = (unsigned short*)d_ws;
    int*   cnt        = (int*)(xb + (size_t)N_NODES * 128);
    int*   row_start  = cnt + N_NODES;
    float* dinv       = (float*)(row_start + N_NODES);
    int*   esrc       = (int*)(dinv + N_NODES);
    unsigned int* pbuf = (unsigned int*)(esrc + (size_t)NB * CAPB);
    float* bv         = (float*)(pbuf + (size_t)NB * CAPB);
    unsigned short* Wp = (unsigned short*)(bv + D);
    int*   gcur       = (int*)(Wp + 256 * D);

    k_init<<<1, 512, 0, stream>>>(gcur);
    k_a<<<KA_BLOCKS, 256, 0, stream>>>(src, dst, gcur, pbuf, Wc, W0, Wt, bc, x,
                                       Wp, bv, xb);
    k_part2<<<NB, 256, 0, stream>>>(pbuf, gcur, row_start, cnt, dinv, esrc);
    k_gmm<<<(N_NODES + 63) / 64, 512, 0, stream>>>(xb, row_start, cnt, dinv, esrc,
                                                   Wp, bv, out);
}